// Round 1
// baseline (106.025 us; speedup 1.0000x reference)
//
#include <hip/hip_runtime.h>

// Problem constants (from reference): B=32, N=1024, F_IN=128, D=128
#define B   32
#define N   1024
#define FIN 128
#define DD  128
#define CH  8      // chunks of rows per batch
#define ROWS 128   // rows per chunk (N/CH)

// Workspace layout (float offsets). Total ~103200 floats (~413 KB).
#define OFF_PASUM 0        // [B][CH][FIN] partial column sums of atom_query
#define OFF_AGG   32768    // [B][N]       masked agg logits
#define OFF_WPART 65536    // [B][CH][FIN] per-chunk online-softmax weighted aq sums
#define OFF_MPART 98304    // [B][CH]      per-chunk running max
#define OFF_LPART 98560    // [B][CH]      per-chunk exp-sum
#define OFF_SPART 98816    // [B][CH]      per-chunk masked exp-sum
#define OFF_U     99072    // [B][FIN]     u = Wq @ ksum
#define OFF_C     103168   // [B]          c = bq . ksum

// ---------------- Kernel A: asum partials -----------------------------------
// grid 256 (= B*CH), block 256. Each block sums 128 rows of aq into 128 floats.
__global__ __launch_bounds__(256) void k_asum(const float* __restrict__ aq,
                                              float* __restrict__ ws) {
    const int b = blockIdx.x >> 3, ch = blockIdx.x & 7;
    const int f4 = threadIdx.x & 31;     // float4 index within the 128-wide row
    const int g  = threadIdx.x >> 5;     // 8 row groups
    const float4* aq4 = (const float4*)aq + (size_t)(b * N + ch * ROWS) * 32;
    float4 acc = make_float4(0.f, 0.f, 0.f, 0.f);
    for (int j = 0; j < 16; ++j) {
        const int n = g + 8 * j;               // consecutive rows across the wave
        float4 v = aq4[n * 32 + f4];           // 16B coalesced
        acc.x += v.x; acc.y += v.y; acc.z += v.z; acc.w += v.w;
    }
    __shared__ float4 sh[256];
    sh[threadIdx.x] = acc;
    __syncthreads();
    if (threadIdx.x < 32) {
        float4 r = sh[threadIdx.x];
        for (int gg = 1; gg < 8; ++gg) {
            float4 t = sh[gg * 32 + threadIdx.x];
            r.x += t.x; r.y += t.y; r.z += t.z; r.w += t.w;
        }
        float4* outp = (float4*)(ws + OFF_PASUM) + (b * CH + ch) * 32;
        outp[threadIdx.x] = r;
    }
}

// ---------------- Kernel B: tiny prep (ksum, u, c) --------------------------
// grid B, block 128.
__global__ __launch_bounds__(128) void k_prep(const float* __restrict__ Wq,
                                              const float* __restrict__ bq,
                                              const float* __restrict__ Wk,
                                              const float* __restrict__ bk,
                                              float* __restrict__ ws) {
    const int b = blockIdx.x, t = threadIdx.x;
    __shared__ float asum[FIN], ksum[DD];
    float a = 0.f;
    for (int ch = 0; ch < CH; ++ch) a += ws[OFF_PASUM + (b * CH + ch) * FIN + t];
    asum[t] = a;
    __syncthreads();
    float ks = 1024.0f * bk[t];                       // N * bk
    for (int f = 0; f < FIN; ++f) ks += asum[f] * Wk[f * DD + t];  // coalesced over t
    ksum[t] = ks;
    __syncthreads();
    float uu = 0.f;
    for (int d = 0; d < DD; ++d) uu += Wq[t * DD + d] * ksum[d];
    ws[OFF_U + b * FIN + t] = uu;
    if (t == 0) {
        float cc = 0.f;
        for (int d = 0; d < DD; ++d) cc += bq[d] * ksum[d];
        ws[OFF_C + b] = cc;
    }
}

// ---------------- Kernel C1: agg + online-softmax weighted sums -------------
// grid 256 (= B*CH), block 256 (4 waves, 32 rows per wave).
__global__ __launch_bounds__(256) void k_agg(const float* __restrict__ aq,
                                             const float* __restrict__ mask,
                                             float* __restrict__ ws) {
    const int b = blockIdx.x >> 3, ch = blockIdx.x & 7;
    const int tid = threadIdx.x, lane = tid & 63, w = tid >> 6;
    __shared__ float u_s[FIN];
    __shared__ float sh_m[4], sh_l[4], sh_s[4], sh_w[4 * FIN];
    if (tid < FIN) u_s[tid] = ws[OFF_U + b * FIN + tid];
    const float c_b = ws[OFF_C + b];
    __syncthreads();

    const float dk = 0.08838834764831845f;  // 128^-0.5
    float mw = -1e30f, lw = 0.f, sacc = 0.f, w0 = 0.f, w1 = 0.f;
    const int n0 = ch * ROWS + w * 32;
    const float* aqb = aq + (size_t)b * N * FIN;
    for (int r = 0; r < 32; ++r) {
        const int n = n0 + r;
        const float a0 = aqb[n * FIN + lane];        // coalesced 256B
        const float a1 = aqb[n * FIN + 64 + lane];
        float v = a0 * u_s[lane] + a1 * u_s[lane + 64];
        for (int off = 32; off > 0; off >>= 1) v += __shfl_xor(v, off);
        const float m = mask[b * N + n];             // broadcast load
        const float raw = dk * (v + c_b);
        const float aggv = m * raw + (1.0f - m) * (-1e9f);
        if (lane == 0) ws[OFF_AGG + b * N + n] = aggv;
        // online softmax accumulation (per-wave)
        const float nm = fmaxf(mw, aggv);
        const float sc = __expf(mw - nm);
        const float p  = __expf(aggv - nm);
        const float mp = m * p;
        lw   = lw * sc + p;
        sacc = sacc * sc + mp;
        w0   = w0 * sc + mp * a0;
        w1   = w1 * sc + mp * a1;
        mw = nm;
    }
    if (lane == 0) { sh_m[w] = mw; sh_l[w] = lw; sh_s[w] = sacc; }
    sh_w[w * FIN + lane]      = w0;
    sh_w[w * FIN + 64 + lane] = w1;
    __syncthreads();
    if (tid < FIN) {
        const float M = fmaxf(fmaxf(sh_m[0], sh_m[1]), fmaxf(sh_m[2], sh_m[3]));
        const float e0 = __expf(sh_m[0] - M), e1 = __expf(sh_m[1] - M);
        const float e2 = __expf(sh_m[2] - M), e3 = __expf(sh_m[3] - M);
        ws[OFF_WPART + (b * CH + ch) * FIN + tid] =
            e0 * sh_w[tid] + e1 * sh_w[FIN + tid] + e2 * sh_w[2 * FIN + tid] + e3 * sh_w[3 * FIN + tid];
        if (tid == 0) {
            ws[OFF_MPART + b * CH + ch] = M;
            ws[OFF_LPART + b * CH + ch] = e0 * sh_l[0] + e1 * sh_l[1] + e2 * sh_l[2] + e3 * sh_l[3];
            ws[OFF_SPART + b * CH + ch] = e0 * sh_s[0] + e1 * sh_s[1] + e2 * sh_s[2] + e3 * sh_s[3];
        }
    }
}

// ---------------- Kernel C2: combine + attn + context -----------------------
// grid B, block 256.
__global__ __launch_bounds__(256) void k_final(const float* __restrict__ Wv,
                                               const float* __restrict__ bv,
                                               const float* __restrict__ ws,
                                               float* __restrict__ out) {
    const int b = blockIdx.x, tid = threadIdx.x;
    float mv[CH];
    float M = -1e30f;
    for (int ch = 0; ch < CH; ++ch) {
        mv[ch] = ws[OFF_MPART + b * CH + ch];
        M = fmaxf(M, mv[ch]);
    }
    float E[CH], L = 0.f, S = 0.f;
    for (int ch = 0; ch < CH; ++ch) {
        E[ch] = __expf(mv[ch] - M);
        L += E[ch] * ws[OFF_LPART + b * CH + ch];
        S += E[ch] * ws[OFF_SPART + b * CH + ch];
    }
    __shared__ float wsh[FIN];
    if (tid < FIN) {
        float wf = 0.f;
        for (int ch = 0; ch < CH; ++ch) wf += E[ch] * ws[OFF_WPART + (b * CH + ch) * FIN + tid];
        wsh[tid] = wf;
    }
    __syncthreads();
    const float invL = 1.0f / L;
    if (tid < FIN) {
        float ctx = 0.f;
        for (int f = 0; f < FIN; ++f) ctx += wsh[f] * Wv[f * DD + tid];  // coalesced over tid
        out[B * N + b * DD + tid] = ctx * invL + S * invL * bv[tid];
    }
    // attn output: exp(agg - M) / L  (masked rows underflow to exactly 0)
    for (int j = 0; j < 4; ++j) {
        const int n = j * 256 + tid;
        out[b * N + n] = __expf(ws[OFF_AGG + b * N + n] - M) * invL;
    }
}

extern "C" void kernel_launch(void* const* d_in, const int* in_sizes, int n_in,
                              void* d_out, int out_size, void* d_ws, size_t ws_size,
                              hipStream_t stream) {
    const float* aq   = (const float*)d_in[0];
    const float* mask = (const float*)d_in[1];
    const float* Wq   = (const float*)d_in[2];
    const float* bq   = (const float*)d_in[3];
    const float* Wk   = (const float*)d_in[4];
    const float* bk   = (const float*)d_in[5];
    const float* Wv   = (const float*)d_in[6];
    const float* bv   = (const float*)d_in[7];
    float* ws  = (float*)d_ws;
    float* out = (float*)d_out;

    k_asum <<<B * CH, 256, 0, stream>>>(aq, ws);
    k_prep <<<B,      128, 0, stream>>>(Wq, bq, Wk, bk, ws);
    k_agg  <<<B * CH, 256, 0, stream>>>(aq, mask, ws);
    k_final<<<B,      256, 0, stream>>>(Wv, bv, ws, out);
}